// Round 5
// baseline (122.252 us; speedup 1.0000x reference)
//
#include <hip/hip_runtime.h>
#include <hip/hip_bf16.h>
#include <stdint.h>

// dist2[b,f] = sum_d s2[f,d]*x2[b,d] - 2*sum_d s2*mu*x + c[f]
//  => GEMM M=4096 N=512 K=1024, bf16 operands A=[x2|x], W=[s2|-2*s2*mu].
// R8 post-mortem: 4x GEMM occupancy change was NEUTRAL (92.8->94.2) — the
// GEMM is a small fraction of dur_us. R9 (this): DECOMPOSITION PROBE.
// Every kernel runs TWICE (all idempotent: gemm now writes loc to ws
// buffer L; softmax reads L, writes out). dur(R9)-dur(R8) ~= P+G+S
// (kernel sum); fixed floor C = dur(R8) - that. Decides whether remaining
// effort goes into kernels or into dispatch-count/structure.
#define BB 4096
#define FF 512
#define DD 512
#define KDIM 1024

typedef __bf16 bf16x8 __attribute__((ext_vector_type(8)));
typedef float f32x4 __attribute__((ext_vector_type(4)));
typedef unsigned short u16x8 __attribute__((ext_vector_type(8)));

__device__ __forceinline__ unsigned short f2bf(float f) {
  unsigned u = __builtin_bit_cast(unsigned, f);
  u += 0x7FFFu + ((u >> 16) & 1u);   // RNE
  return (unsigned short)(u >> 16);
}

__device__ __forceinline__ void async16(const void* g, void* l) {
  auto gp = reinterpret_cast<const __attribute__((address_space(1))) uint32_t*>(
      reinterpret_cast<uintptr_t>(g));
  auto lp = reinterpret_cast<__attribute__((address_space(3))) uint32_t*>(
      reinterpret_cast<uintptr_t>(l));
  __builtin_amdgcn_global_load_lds(gp, lp, 16, 0, 0);
}

// ---------------- prep: blocks [0,512) build W + c; blocks [512,1536) build A
__global__ __launch_bounds__(256) void prep_kernel(
    const float* __restrict__ x, const float* __restrict__ mu,
    const float* __restrict__ sg, unsigned short* __restrict__ A,
    unsigned short* __restrict__ W, float* __restrict__ c) {
  __shared__ float red[4];
  const int bid = blockIdx.x;
  const int t = threadIdx.x;
  if (bid < FF) {
    const int f = bid;
    float part = 0.f;
#pragma unroll
    for (int dd = 0; dd < 2; ++dd) {
      const int d = t + dd * 256;
      const float m = mu[f * DD + d];
      const float s = sg[f * DD + d];
      const float s2 = s * s;
      W[f * KDIM + d] = f2bf(s2);
      W[f * KDIM + DD + d] = f2bf(-2.f * s2 * m);
      part += s2 * m * m;
    }
#pragma unroll
    for (int off = 32; off > 0; off >>= 1) part += __shfl_down(part, off, 64);
    const int lane = t & 63, wave = t >> 6;
    if (lane == 0) red[wave] = part;
    __syncthreads();
    if (t == 0) c[f] = red[0] + red[1] + red[2] + red[3];
  } else {
    const int gid = (bid - FF) * 256 + t;     // 1024 blocks cover B*D/8
    const int i8 = gid * 8;
    const float4 v0 = *(const float4*)(x + i8);
    const float4 v1 = *(const float4*)(x + i8 + 4);
    const int b = i8 >> 9;
    const int d = i8 & 511;
    u16x8 q2, q1;
    q2[0] = f2bf(v0.x * v0.x); q2[1] = f2bf(v0.y * v0.y);
    q2[2] = f2bf(v0.z * v0.z); q2[3] = f2bf(v0.w * v0.w);
    q2[4] = f2bf(v1.x * v1.x); q2[5] = f2bf(v1.y * v1.y);
    q2[6] = f2bf(v1.z * v1.z); q2[7] = f2bf(v1.w * v1.w);
    q1[0] = f2bf(v0.x); q1[1] = f2bf(v0.y); q1[2] = f2bf(v0.z); q1[3] = f2bf(v0.w);
    q1[4] = f2bf(v1.x); q1[5] = f2bf(v1.y); q1[6] = f2bf(v1.z); q1[7] = f2bf(v1.w);
    *(u16x8*)(A + (size_t)b * KDIM + d) = q2;
    *(u16x8*)(A + (size_t)b * KDIM + DD + d) = q1;
  }
}

// ---------------- GEMM: block 32(M)x64(N), grid 1024 = 4 blocks/CU.
// Writes loc to L (workspace) so softmax can be out-of-place/idempotent.
__global__ __launch_bounds__(256) void gemm_kernel(
    const unsigned short* __restrict__ A, const unsigned short* __restrict__ W,
    const float* __restrict__ c, float* __restrict__ L) {
  __shared__ __align__(16) unsigned short As[2][32 * 64];
  const int bid = blockIdx.x;
  const int xcd = bid & 7;
  const int l = bid >> 3;                    // 0..127
  const int m0 = (xcd * 16 + (l & 15)) * 32;
  const int n0 = (l >> 4) * 64;
  const int tid = threadIdx.x;
  const int lane = tid & 63;
  const int wave = tid >> 6;

  f32x4 acc[2];
  acc[0] = (f32x4){0.f, 0.f, 0.f, 0.f};
  acc[1] = (f32x4){0.f, 0.f, 0.f, 0.f};

  const int srow = lane >> 3;
  const int sc16 = lane & 7;
  const int gcol = (sc16 ^ srow) * 8;
  const int quad = lane >> 4;
  const int r = lane & 15;

  const unsigned short* ag = A + (size_t)(m0 + wave * 8 + srow) * KDIM + gcol;
  const int arb = wave * 8 * 64;
  const unsigned short* wg0 = W + (size_t)(n0 + wave * 16 + r) * KDIM + quad * 8;

  async16(ag, &As[0][arb]);
  bf16x8 bc[2], bn[2];
  bc[0] = *(const bf16x8*)(wg0);
  bc[1] = *(const bf16x8*)(wg0 + 32);

  for (int kt = 0; kt < KDIM / 64; ++kt) {
    const int cur = kt & 1;
    __syncthreads();
    if (kt + 1 < KDIM / 64) {
      const int k1 = (kt + 1) * 64;
      async16(ag + k1, &As[cur ^ 1][arb]);
      bn[0] = *(const bf16x8*)(wg0 + k1);
      bn[1] = *(const bf16x8*)(wg0 + k1 + 32);
    }
#pragma unroll
    for (int kk = 0; kk < 2; ++kk) {
      const int pc = ((kk * 4 + quad) ^ (r & 7)) * 8;
#pragma unroll
      for (int mt = 0; mt < 2; ++mt) {
        bf16x8 a = *(const bf16x8*)&As[cur][(mt * 16 + r) * 64 + pc];
        acc[mt] = __builtin_amdgcn_mfma_f32_16x16x32_bf16(a, bc[kk], acc[mt], 0, 0, 0);
      }
    }
    bc[0] = bn[0];
    bc[1] = bn[1];
  }

  const int f = n0 + wave * 16 + r;
  const float cf = c[f];
#pragma unroll
  for (int mt = 0; mt < 2; ++mt) {
    const int mbase = m0 + mt * 16 + quad * 4;
#pragma unroll
    for (int rr = 0; rr < 4; ++rr) {
      const float d2 = acc[mt][rr] + cf;
      const float loc = __expf(-sqrtf(fmaxf(d2, 0.f)));
      L[(size_t)(mbase + rr) * FF + f] = loc;
    }
  }
}

// ---------------- softmax: out-of-place (reads L, writes out) => idempotent
__global__ __launch_bounds__(256) void softmax_kernel(
    const float* __restrict__ L, float* __restrict__ out,
    const float* __restrict__ temp) {
  const int lane = threadIdx.x & 63;
  const int wave = threadIdx.x >> 6;
  const int row = blockIdx.x * 4 + wave;
  const float s = 1.f / (1.f + __expf(-temp[0]));
  const float4* p = (const float4*)(L + (size_t)row * FF + lane * 8);
  float4* q = (float4*)(out + (size_t)row * FF + lane * 8);
  const float4 v0 = p[0];
  const float4 v1 = p[1];
  float l[8] = {v0.x * s, v0.y * s, v0.z * s, v0.w * s,
                v1.x * s, v1.y * s, v1.z * s, v1.w * s};
  float mx = l[0];
#pragma unroll
  for (int i = 1; i < 8; ++i) mx = fmaxf(mx, l[i]);
#pragma unroll
  for (int off = 32; off > 0; off >>= 1) mx = fmaxf(mx, __shfl_xor(mx, off, 64));
  float e[8], sum = 0.f;
#pragma unroll
  for (int i = 0; i < 8; ++i) { e[i] = __expf(l[i] - mx); sum += e[i]; }
#pragma unroll
  for (int off = 32; off > 0; off >>= 1) sum += __shfl_xor(sum, off, 64);
  const float inv = 1.f / sum;
  float4 w0 = {e[0] * inv, e[1] * inv, e[2] * inv, e[3] * inv};
  float4 w1 = {e[4] * inv, e[5] * inv, e[6] * inv, e[7] * inv};
  q[0] = w0; q[1] = w1;
}

// ---------------- fallback (no workspace): fp32 direct + in-place softmax
__global__ __launch_bounds__(256) void naive_loc(
    const float* __restrict__ x, const float* __restrict__ mu,
    const float* __restrict__ sg, float* __restrict__ out) {
  __shared__ float xs[DD];
  const int b = blockIdx.x;
  for (int d = threadIdx.x; d < DD; d += 256) xs[d] = x[(size_t)b * DD + d];
  __syncthreads();
  for (int f = threadIdx.x; f < FF; f += 256) {
    float acc = 0.f;
    for (int d = 0; d < DD; ++d) {
      const float s = sg[(size_t)f * DD + d];
      const float df = (xs[d] - mu[(size_t)f * DD + d]) * s;
      acc = fmaf(df, df, acc);
    }
    out[(size_t)b * FF + f] = __expf(-sqrtf(acc));
  }
}

__global__ __launch_bounds__(256) void softmax_inplace(
    float* __restrict__ out, const float* __restrict__ temp) {
  const int lane = threadIdx.x & 63;
  const int wave = threadIdx.x >> 6;
  const int row = blockIdx.x * 4 + wave;
  const float s = 1.f / (1.f + __expf(-temp[0]));
  float4* p = (float4*)(out + (size_t)row * FF + lane * 8);
  const float4 v0 = p[0];
  const float4 v1 = p[1];
  float l[8] = {v0.x * s, v0.y * s, v0.z * s, v0.w * s,
                v1.x * s, v1.y * s, v1.z * s, v1.w * s};
  float mx = l[0];
#pragma unroll
  for (int i = 1; i < 8; ++i) mx = fmaxf(mx, l[i]);
#pragma unroll
  for (int off = 32; off > 0; off >>= 1) mx = fmaxf(mx, __shfl_xor(mx, off, 64));
  float e[8], sum = 0.f;
#pragma unroll
  for (int i = 0; i < 8; ++i) { e[i] = __expf(l[i] - mx); sum += e[i]; }
#pragma unroll
  for (int off = 32; off > 0; off >>= 1) sum += __shfl_xor(sum, off, 64);
  const float inv = 1.f / sum;
  float4 w0 = {e[0] * inv, e[1] * inv, e[2] * inv, e[3] * inv};
  float4 w1 = {e[4] * inv, e[5] * inv, e[6] * inv, e[7] * inv};
  p[0] = w0; p[1] = w1;
}

extern "C" void kernel_launch(void* const* d_in, const int* in_sizes, int n_in,
                              void* d_out, int out_size, void* d_ws, size_t ws_size,
                              hipStream_t stream) {
  const float* x = (const float*)d_in[0];
  const float* mu = (const float*)d_in[1];
  const float* sg = (const float*)d_in[2];
  const float* temp = (const float*)d_in[3];
  float* out = (float*)d_out;

  const size_t needA = (size_t)BB * KDIM * 2;          // 8 MB
  const size_t needW = (size_t)FF * KDIM * 2;          // 1 MB
  const size_t needC = (size_t)FF * 4;                 // 2 KB
  const size_t needL = (size_t)BB * FF * 4;            // 8 MB
  if (ws_size >= needA + needW + needC + needL) {
    unsigned short* A = (unsigned short*)d_ws;
    unsigned short* W = A + (size_t)BB * KDIM;
    float* c = (float*)(W + (size_t)FF * KDIM);
    float* L = c + FF;
    // PROBE: each kernel twice (all idempotent). Delta vs R8 = P+G+S.
    prep_kernel<<<FF + (BB * DD / 8) / 256, 256, 0, stream>>>(x, mu, sg, A, W, c);
    prep_kernel<<<FF + (BB * DD / 8) / 256, 256, 0, stream>>>(x, mu, sg, A, W, c);
    gemm_kernel<<<1024, 256, 0, stream>>>(A, W, c, L);
    gemm_kernel<<<1024, 256, 0, stream>>>(A, W, c, L);
    softmax_kernel<<<BB / 4, 256, 0, stream>>>(L, out, temp);
    softmax_kernel<<<BB / 4, 256, 0, stream>>>(L, out, temp);
  } else {
    naive_loc<<<BB, 256, 0, stream>>>(x, mu, sg, out);
    softmax_inplace<<<BB / 4, 256, 0, stream>>>(out, temp);
  }
}

// Round 6
// 99.987 us; speedup vs baseline: 1.2227x; 1.2227x over previous
//
#include <hip/hip_runtime.h>
#include <hip/hip_bf16.h>
#include <stdint.h>

// dist2[b,f] = sum_d s2[f,d]*x2[b,d] - 2*sum_d s2*mu*x + c[f]
//  => GEMM M=4096 N=512 K=1024, bf16 A=[x2|x] (built in-LDS), W=[s2|-2*s2*mu].
// R9 probe: kernel-sum P+G+S ~= 28us, fixed floor C ~= 66us (41.5us harness
// workspace re-poison + ~25us graph/dispatch overhead). R10 (this):
//  - 2 dispatches instead of 3 (softmax fused into GEMM epilogue).
//  - A never materialized: block's A-tile (16 x 1024 bf16 = 32KB) built in
//    LDS from x directly; K-loop has ZERO barriers (no per-step staging).
//  - tile 16M x 512N(full row), 512 thr / 8 waves, grid 256 (1 block/CU,
//    2 waves/SIMD); W streamed from L2 (1MB, resident per XCD).
//  - row softmax: in-reg nt-reduce -> shfl_xor over 16-lane col group ->
//    8-wave LDS combine (2 barriers, 1KB LDS).
#define BB 4096
#define FF 512
#define DD 512
#define KDIM 1024

typedef __bf16 bf16x8 __attribute__((ext_vector_type(8)));
typedef float f32x4 __attribute__((ext_vector_type(4)));
typedef unsigned short u16x8 __attribute__((ext_vector_type(8)));

__device__ __forceinline__ unsigned short f2bf(float f) {
  unsigned u = __builtin_bit_cast(unsigned, f);
  u += 0x7FFFu + ((u >> 16) & 1u);   // RNE
  return (unsigned short)(u >> 16);
}

// ---------------- prep: 512 blocks, one f-row each: build W + c
__global__ __launch_bounds__(256) void prep_kernel(
    const float* __restrict__ mu, const float* __restrict__ sg,
    unsigned short* __restrict__ W, float* __restrict__ c) {
  __shared__ float red[4];
  const int f = blockIdx.x;
  const int t = threadIdx.x;
  float part = 0.f;
#pragma unroll
  for (int dd = 0; dd < 2; ++dd) {
    const int d = t + dd * 256;
    const float m = mu[f * DD + d];
    const float s = sg[f * DD + d];
    const float s2 = s * s;
    W[f * KDIM + d] = f2bf(s2);
    W[f * KDIM + DD + d] = f2bf(-2.f * s2 * m);
    part += s2 * m * m;
  }
#pragma unroll
  for (int off = 32; off > 0; off >>= 1) part += __shfl_down(part, off, 64);
  const int lane = t & 63, wave = t >> 6;
  if (lane == 0) red[wave] = part;
  __syncthreads();
  if (t == 0) c[f] = red[0] + red[1] + red[2] + red[3];
}

// ---------------- fused GEMM + row-softmax
// block: 16 M-rows x 512 N-cols, 8 waves each 16x64 (4 n-tiles), grid 256.
__global__ __launch_bounds__(512) void gemm_sm_kernel(
    const float* __restrict__ x, const unsigned short* __restrict__ W,
    const float* __restrict__ c, const float* __restrict__ temp,
    float* __restrict__ out) {
  __shared__ __align__(16) unsigned short As[16 * 1024];  // 32KB, XOR-swizzled
  __shared__ float redmax[8][16];
  __shared__ float redsum[8][16];

  const int bid = blockIdx.x;          // 0..255
  const int m0 = bid * 16;
  const int tid = threadIdx.x;
  const int lane = tid & 63;
  const int wave = tid >> 6;           // 0..7
  const int quad = lane >> 4;
  const int r = lane & 15;
  const int wn = wave * 64;            // wave's N-slice base

  // ---- build A-tile in LDS: row b, cols [0,512)=x^2, [512,1024)=x (bf16)
  // 16B chunk cl of row lives at phys chunk cl ^ (row&7)  (conflict-free
  // ds_read_b128 later: rows 0-7 distinct slots, 8-15 repeat = 2-way free).
  {
    const int row = tid >> 5;           // 16 rows, 32 threads each
    const int dbase = (tid & 31) * 16;  // 16 fp32 per thread (64B coalesced)
    const float* xr = x + (size_t)(m0 + row) * DD + dbase;
    const float4 v0 = ((const float4*)xr)[0];
    const float4 v1 = ((const float4*)xr)[1];
    const float4 v2 = ((const float4*)xr)[2];
    const float4 v3 = ((const float4*)xr)[3];
    u16x8 qa, qb, pa, pb;
    qa[0] = f2bf(v0.x * v0.x); qa[1] = f2bf(v0.y * v0.y);
    qa[2] = f2bf(v0.z * v0.z); qa[3] = f2bf(v0.w * v0.w);
    qa[4] = f2bf(v1.x * v1.x); qa[5] = f2bf(v1.y * v1.y);
    qa[6] = f2bf(v1.z * v1.z); qa[7] = f2bf(v1.w * v1.w);
    qb[0] = f2bf(v2.x * v2.x); qb[1] = f2bf(v2.y * v2.y);
    qb[2] = f2bf(v2.z * v2.z); qb[3] = f2bf(v2.w * v2.w);
    qb[4] = f2bf(v3.x * v3.x); qb[5] = f2bf(v3.y * v3.y);
    qb[6] = f2bf(v3.z * v3.z); qb[7] = f2bf(v3.w * v3.w);
    pa[0] = f2bf(v0.x); pa[1] = f2bf(v0.y); pa[2] = f2bf(v0.z); pa[3] = f2bf(v0.w);
    pa[4] = f2bf(v1.x); pa[5] = f2bf(v1.y); pa[6] = f2bf(v1.z); pa[7] = f2bf(v1.w);
    pb[0] = f2bf(v2.x); pb[1] = f2bf(v2.y); pb[2] = f2bf(v2.z); pb[3] = f2bf(v2.w);
    pb[4] = f2bf(v3.x); pb[5] = f2bf(v3.y); pb[6] = f2bf(v3.z); pb[7] = f2bf(v3.w);
    const int swz = row & 7;
    const int cbase = dbase >> 3;       // even chunk index 0..62
    unsigned short* rb = &As[row * 1024];
    *(u16x8*)&rb[((cbase) ^ swz) * 8] = qa;
    *(u16x8*)&rb[((cbase + 1) ^ swz) * 8] = qb;
    *(u16x8*)&rb[((64 + cbase) ^ swz) * 8] = pa;
    *(u16x8*)&rb[((64 + cbase + 1) ^ swz) * 8] = pb;
  }
  __syncthreads();   // the ONLY barrier before the epilogue

  // ---- K-loop: no barriers, no staging. B streamed global(L2)->VGPR with
  // one-step prefetch; A from LDS (2 ds_read_b128 per step).
  f32x4 acc[4];
#pragma unroll
  for (int nt = 0; nt < 4; ++nt) acc[nt] = (f32x4){0.f, 0.f, 0.f, 0.f};

  const unsigned short* wg0 = W + (size_t)(wn + r) * KDIM + quad * 8;
  const int aswz = r & 7;

  bf16x8 bc[2][4], bn[2][4];
#pragma unroll
  for (int kk = 0; kk < 2; ++kk)
#pragma unroll
    for (int nt = 0; nt < 4; ++nt)
      bc[kk][nt] = *(const bf16x8*)(wg0 + (size_t)nt * 16 * KDIM + kk * 32);

#pragma unroll
  for (int kt = 0; kt < KDIM / 64; ++kt) {
    if (kt + 1 < KDIM / 64) {
      const int k1 = (kt + 1) * 64;
#pragma unroll
      for (int kk = 0; kk < 2; ++kk)
#pragma unroll
        for (int nt = 0; nt < 4; ++nt)
          bn[kk][nt] = *(const bf16x8*)(wg0 + (size_t)nt * 16 * KDIM + k1 + kk * 32);
    }
#pragma unroll
    for (int kk = 0; kk < 2; ++kk) {
      const int chunk = (kt * 8 + kk * 4 + quad) ^ aswz;
      bf16x8 a = *(const bf16x8*)&As[r * 1024 + chunk * 8];
#pragma unroll
      for (int nt = 0; nt < 4; ++nt)
        acc[nt] = __builtin_amdgcn_mfma_f32_16x16x32_bf16(a, bc[kk][nt], acc[nt], 0, 0, 0);
    }
#pragma unroll
    for (int kk = 0; kk < 2; ++kk)
#pragma unroll
      for (int nt = 0; nt < 4; ++nt) bc[kk][nt] = bn[kk][nt];
  }

  // ---- epilogue: loc = exp(-sqrt(d2)); fused row softmax over 512 cols.
  // D layout: m-row = quad*4+rr, f-col = wn + nt*16 + r.
  const float s = 1.f / (1.f + __expf(-temp[0]));
  float cf[4];
#pragma unroll
  for (int nt = 0; nt < 4; ++nt) cf[nt] = c[wn + nt * 16 + r];

  float l[4][4];   // [nt][rr] = s * loc
#pragma unroll
  for (int nt = 0; nt < 4; ++nt)
#pragma unroll
    for (int rr = 0; rr < 4; ++rr) {
      const float d2 = acc[nt][rr] + cf[nt];
      l[nt][rr] = s * __expf(-sqrtf(fmaxf(d2, 0.f)));
    }

  // per-row max over this wave's 64 cols
  float pm[4];
#pragma unroll
  for (int rr = 0; rr < 4; ++rr) {
    float m = fmaxf(fmaxf(l[0][rr], l[1][rr]), fmaxf(l[2][rr], l[3][rr]));
#pragma unroll
    for (int off = 1; off < 16; off <<= 1) m = fmaxf(m, __shfl_xor(m, off, 64));
    pm[rr] = m;
  }
  if (r == 0) {
#pragma unroll
    for (int rr = 0; rr < 4; ++rr) redmax[wave][quad * 4 + rr] = pm[rr];
  }
  __syncthreads();
  float rmax[4];
#pragma unroll
  for (int rr = 0; rr < 4; ++rr) {
    const int row = quad * 4 + rr;
    float m = redmax[0][row];
#pragma unroll
    for (int w = 1; w < 8; ++w) m = fmaxf(m, redmax[w][row]);
    rmax[rr] = m;
  }

  float e[4][4], ps[4];
#pragma unroll
  for (int rr = 0; rr < 4; ++rr) {
    float sum = 0.f;
#pragma unroll
    for (int nt = 0; nt < 4; ++nt) {
      e[nt][rr] = __expf(l[nt][rr] - rmax[rr]);
      sum += e[nt][rr];
    }
#pragma unroll
    for (int off = 1; off < 16; off <<= 1) sum += __shfl_xor(sum, off, 64);
    ps[rr] = sum;
  }
  if (r == 0) {
#pragma unroll
    for (int rr = 0; rr < 4; ++rr) redsum[wave][quad * 4 + rr] = ps[rr];
  }
  __syncthreads();
#pragma unroll
  for (int rr = 0; rr < 4; ++rr) {
    const int row = quad * 4 + rr;
    float sum = redsum[0][row];
#pragma unroll
    for (int w = 1; w < 8; ++w) sum += redsum[w][row];
    const float inv = 1.f / sum;
#pragma unroll
    for (int nt = 0; nt < 4; ++nt)
      out[(size_t)(m0 + row) * FF + wn + nt * 16 + r] = e[nt][rr] * inv;
  }
}

// ---------------- fallback (no workspace): fp32 direct + in-place softmax
__global__ __launch_bounds__(256) void naive_loc(
    const float* __restrict__ x, const float* __restrict__ mu,
    const float* __restrict__ sg, float* __restrict__ out) {
  __shared__ float xs[DD];
  const int b = blockIdx.x;
  for (int d = threadIdx.x; d < DD; d += 256) xs[d] = x[(size_t)b * DD + d];
  __syncthreads();
  for (int f = threadIdx.x; f < FF; f += 256) {
    float acc = 0.f;
    for (int d = 0; d < DD; ++d) {
      const float s = sg[(size_t)f * DD + d];
      const float df = (xs[d] - mu[(size_t)f * DD + d]) * s;
      acc = fmaf(df, df, acc);
    }
    out[(size_t)b * FF + f] = __expf(-sqrtf(acc));
  }
}

__global__ __launch_bounds__(256) void softmax_inplace(
    float* __restrict__ out, const float* __restrict__ temp) {
  const int lane = threadIdx.x & 63;
  const int wave = threadIdx.x >> 6;
  const int row = blockIdx.x * 4 + wave;
  const float s = 1.f / (1.f + __expf(-temp[0]));
  float4* p = (float4*)(out + (size_t)row * FF + lane * 8);
  const float4 v0 = p[0];
  const float4 v1 = p[1];
  float l[8] = {v0.x * s, v0.y * s, v0.z * s, v0.w * s,
                v1.x * s, v1.y * s, v1.z * s, v1.w * s};
  float mx = l[0];
#pragma unroll
  for (int i = 1; i < 8; ++i) mx = fmaxf(mx, l[i]);
#pragma unroll
  for (int off = 32; off > 0; off >>= 1) mx = fmaxf(mx, __shfl_xor(mx, off, 64));
  float e[8], sum = 0.f;
#pragma unroll
  for (int i = 0; i < 8; ++i) { e[i] = __expf(l[i] - mx); sum += e[i]; }
#pragma unroll
  for (int off = 32; off > 0; off >>= 1) sum += __shfl_xor(sum, off, 64);
  const float inv = 1.f / sum;
  float4 w0 = {e[0] * inv, e[1] * inv, e[2] * inv, e[3] * inv};
  float4 w1 = {e[4] * inv, e[5] * inv, e[6] * inv, e[7] * inv};
  p[0] = w0; p[1] = w1;
}

extern "C" void kernel_launch(void* const* d_in, const int* in_sizes, int n_in,
                              void* d_out, int out_size, void* d_ws, size_t ws_size,
                              hipStream_t stream) {
  const float* x = (const float*)d_in[0];
  const float* mu = (const float*)d_in[1];
  const float* sg = (const float*)d_in[2];
  const float* temp = (const float*)d_in[3];
  float* out = (float*)d_out;

  const size_t needW = (size_t)FF * KDIM * 2;          // 1 MB
  const size_t needC = (size_t)FF * 4;                 // 2 KB
  if (ws_size >= needW + needC) {
    unsigned short* W = (unsigned short*)d_ws;
    float* c = (float*)(W + (size_t)FF * KDIM);
    prep_kernel<<<FF, 256, 0, stream>>>(mu, sg, W, c);
    gemm_sm_kernel<<<256, 512, 0, stream>>>(x, W, c, temp, out);
  } else {
    naive_loc<<<BB, 256, 0, stream>>>(x, mu, sg, out);
    softmax_inplace<<<BB / 4, 256, 0, stream>>>(out, temp);
  }
}